// Round 8
// baseline (310.892 us; speedup 1.0000x reference)
//
#include <hip/hip_runtime.h>
#include <hip/hip_bf16.h>
#include <stdint.h>

// Problem constants
#define B_    2
#define S_    2048
#define D_    1024
#define H_    16
#define NTOK  (B_ * S_)   // 4096

typedef __attribute__((ext_vector_type(8))) short bf16x8;
typedef __attribute__((ext_vector_type(4))) float f32x4;
typedef __attribute__((ext_vector_type(2))) float float2v;
typedef __attribute__((ext_vector_type(2))) __bf16 bfv2;

// packed pair fp32 -> 2x bf16 (v_cvt_pk_bf16_f32, RNE)
static __device__ __forceinline__ unsigned int pkbf(float a, float b) {
    float2v fv = {a, b};
    bfv2 r = __builtin_convertvector(fv, bfv2);
    unsigned int u;
    __builtin_memcpy(&u, &r, 4);
    return u;
}

// async global->LDS, 16 B per lane; LDS dest = wave-uniform base + lane*16
using g_cu32 = __attribute__((address_space(1))) const unsigned int;
using l_u32  = __attribute__((address_space(3))) unsigned int;
static __device__ __forceinline__ void gld16(const void* g, void* l) {
    __builtin_amdgcn_global_load_lds((g_cu32*)g, (l_u32*)l, 16, 0, 0);
}

// counted vmcnt wait (T4)
template<int N> static __device__ __forceinline__ void wait_vm() {
    if constexpr (N == 0)      asm volatile("s_waitcnt vmcnt(0)" ::: "memory");
    else if constexpr (N == 2) asm volatile("s_waitcnt vmcnt(2)" ::: "memory");
    else if constexpr (N == 4) asm volatile("s_waitcnt vmcnt(4)" ::: "memory");
    else if constexpr (N == 8) asm volatile("s_waitcnt vmcnt(8)" ::: "memory");
}
static __device__ __forceinline__ void wait_lgkm0() {
    asm volatile("s_waitcnt lgkmcnt(0)" ::: "memory");
}

#define QN ((size_t)NTOK * D_)   // 4194304
#define WN ((size_t)D_ * D_)     // 1048576 = 1<<20

// ---------------------------------------------------------------------------
// prep: blocks [0,8192) = fp32->bf16 bulk convert (q,k,v + 4 weights);
//       blocks [8192,9216) = mask tile flags (flags[qt][kt] = any-zero in 64x64).
// ---------------------------------------------------------------------------
__global__ __launch_bounds__(256) void prep_kernel(
    const float* __restrict__ q, const float* __restrict__ k, const float* __restrict__ v,
    const float* __restrict__ Wq, const float* __restrict__ Wk,
    const float* __restrict__ Wv, const float* __restrict__ Wo,
    const int* __restrict__ mask,
    unsigned short* __restrict__ qb, unsigned short* __restrict__ kb,
    unsigned short* __restrict__ vb, unsigned short* __restrict__ wqb,
    unsigned short* __restrict__ wkb, unsigned short* __restrict__ wvb,
    unsigned short* __restrict__ wob, int* __restrict__ flags) {
    __shared__ int anyz;
    if (blockIdx.x < 8192) {
        size_t i = ((size_t)blockIdx.x * 256 + threadIdx.x) * 8;
        const float* s; unsigned short* d; size_t off;
        if (i < QN)          { s = q; d = qb; off = i; }
        else if (i < 2 * QN) { s = k; d = kb; off = i - QN; }
        else if (i < 3 * QN) { s = v; d = vb; off = i - 2 * QN; }
        else {
            size_t j = i - 3 * QN;
            int wi = (int)(j >> 20);
            s = (wi == 0) ? Wq : (wi == 1) ? Wk : (wi == 2) ? Wv : Wo;
            d = (wi == 0) ? wqb : (wi == 1) ? wkb : (wi == 2) ? wvb : wob;
            off = j & (WN - 1);
        }
        float4 a = *(const float4*)(s + off);
        float4 b = *(const float4*)(s + off + 4);
        uint4 pk;
        pk.x = pkbf(a.x, a.y); pk.y = pkbf(a.z, a.w);
        pk.z = pkbf(b.x, b.y); pk.w = pkbf(b.z, b.w);
        *(uint4*)(d + off) = pk;
    } else {
        if (threadIdx.x == 0) anyz = 0;
        __syncthreads();
        int bid2 = blockIdx.x - 8192;
        const int qt = bid2 >> 5, kt = bid2 & 31;
        int az = 0;
        for (int i = threadIdx.x; i < 64 * 64; i += 256) {
            int r = i >> 6, c = i & 63;
            az |= (mask[(size_t)(qt * 64 + r) * S_ + kt * 64 + c] == 0) ? 1 : 0;
        }
        if (az) atomicOr(&anyz, 1);
        __syncthreads();
        if (threadIdx.x == 0) flags[qt * 32 + kt] = anyz;
    }
}

// ---------------------------------------------------------------------------
// R8: staging model validated across R2-R7:
//   time = staged_bytes / (~11 B/cy/CU x active CUs), schedule-invariant.
// -> minimize staged bytes. gemm_qkv: 256x256 tile, BK=64.
// Staged/z = A x (1024/256 = 4 re-reads x 8MB) + W x (4096/256 = 16 x 2MB)
//          = 64 MB -> 192 MB total (vs 393 MB at 128x128 = the 59us configs).
// Grid 192 (16 bx x 4 by x 3 z) = 0.75 blocks/CU (64 CUs idle - byte win
// dominates: predict ~41 us). 8 waves (512 thr), wave grid 2(M)x4(N),
// wave-tile 128x64: per step 64 MFMA, 24 ds_read_b128, 8 gld16 per wave.
// LDS 2 buf x (A 32K + B 32K) = 128 KB. Sync skeleton = R6's gemm_n64
// (correctness-proven): bar1 = counted vmcnt(8) (next tile stays in
// flight), reads, lgkmcnt(0)+bar2, stage into just-freed buffer, MFMA.
// VGPR: kk0 uses per-mi A reads (peak ~180); kk1 preloads frags before
// bar2 so its MFMAs run after the stage (peak ~210 < 256 @ 2 waves/SIMD).
// XCD chunking by-inner: whole W (2 MB/z) stays L2-resident per XCD.
// modes: 1 = bf16 out (Swap: acc = C^T frags), 2 = bf16 Vt layout (NoSwap).
// ---------------------------------------------------------------------------
struct GemmArgs {
    const unsigned short* A[3];
    const unsigned short* W[3];
    const float* bias[3];
    void* C[3];
    int mode[3];
    float scale[3];
};

__global__ __launch_bounds__(512, 2) void gemm_qkv(GemmArgs ga) {
    constexpr int NK = D_ / 64;    // 16 k-steps of BK=64

    // bijective XCD-chunk swizzle: grid 192, 24/XCD; by-inner so each XCD
    // keeps the whole W panel set hot while A panels rotate.
    const int bid = blockIdx.x;
    const int l = (bid & 7) * 24 + (bid >> 3);
    const int z = l >> 6;          // 64 blocks per z
    const int r = l & 63;
    const int bx = r >> 2;         // M tile 0..15
    const int by = r & 3;          // N tile 0..3

    const unsigned short* __restrict__ A = ga.A[z];
    const unsigned short* __restrict__ W = ga.W[z];
    const float* __restrict__ bias = ga.bias[z];
    void* C = ga.C[z];
    const int mode = ga.mode[z];
    const float scl = ga.scale[z];

    // per buffer: 32 groups (16 row-groups x 2 k-halves) x 512 shorts
    __shared__ unsigned short As[2][16384];
    __shared__ unsigned short Bs[2][16384];

    const int t    = threadIdx.x;
    const int lane = t & 63;
    const int w    = t >> 6;       // wave 0..7
    const int fr   = lane & 15;
    const int kq   = lane >> 4;
    const int wrow = w >> 2;       // 0..1 (128 rows each)
    const int wcol = w & 3;        // 0..3 (64 cols each)
    const int m0 = bx * 256, n0 = by * 256;

    const int sc = lane >> 4;      // k-chunk in group
    const int sr = lane & 15;      // row in group

    // staging: wave w owns A groups [4w,4w+4) and B groups [4w,4w+4).
    // group g: kh = g>>4 (k-half), rb = g&15 (16-row block).
    const unsigned short* gA[4];
    const unsigned short* gB[4];
    int loA[4], loB[4];
#pragma unroll
    for (int j = 0; j < 4; ++j) {
        int g = w * 4 + j;
        int kh = g >> 4, rb = g & 15;
        gA[j] = A + (size_t)(m0 + rb * 16 + sr) * D_ + kh * 32 + sc * 8;
        gB[j] = W + (size_t)(n0 + rb * 16 + sr) * D_ + kh * 32 + sc * 8;
        loA[j] = g * 512;
        loB[j] = g * 512;
    }

    int aOff[2][8], bOff[2][4];
#pragma unroll
    for (int kk = 0; kk < 2; ++kk) {
#pragma unroll
        for (int mi = 0; mi < 8; ++mi)
            aOff[kk][mi] = (kk * 16 + wrow * 8 + mi) * 512 + (kq * 16 + fr) * 8;
#pragma unroll
        for (int ni = 0; ni < 4; ++ni)
            bOff[kk][ni] = (kk * 16 + wcol * 4 + ni) * 512 + (kq * 16 + fr) * 8;
    }

    f32x4 acc[8][4];
#pragma unroll
    for (int i = 0; i < 8; ++i)
#pragma unroll
        for (int j = 0; j < 4; ++j) acc[i][j] = (f32x4)0.0f;

    auto stage = [&](int buf) {
#pragma unroll
        for (int j = 0; j < 4; ++j) {
            gld16(gA[j], &As[buf][loA[j]]);
            gld16(gB[j], &Bs[buf][loB[j]]);
            gA[j] += 64; gB[j] += 64;
        }
    };

    const bool swp = (mode != 2);

    stage(0);                      // k-step 0 -> buf 0
    stage(1);                      // k-step 1 -> buf 1
    for (int k0 = 0; k0 < NK; ++k0) {
        const int cur = k0 & 1;
        __builtin_amdgcn_sched_barrier(0);
        if (k0 < NK - 1) wait_vm<8>();     // stage(k0) resident; k0+1 in flight
        else             wait_vm<0>();
        __builtin_amdgcn_s_barrier();      // ... for all waves
        __builtin_amdgcn_sched_barrier(0);

        // kk = 0: B frags upfront, A per-mi (low VGPR pressure)
        {
            bf16x8 bfr[4];
#pragma unroll
            for (int ni = 0; ni < 4; ++ni) bfr[ni] = *(const bf16x8*)&Bs[cur][bOff[0][ni]];
#pragma unroll
            for (int mi = 0; mi < 8; ++mi) {
                bf16x8 a = *(const bf16x8*)&As[cur][aOff[0][mi]];
                if (swp) {
#pragma unroll
                    for (int ni = 0; ni < 4; ++ni)
                        acc[mi][ni] = __builtin_amdgcn_mfma_f32_16x16x32_bf16(
                            bfr[ni], a, acc[mi][ni], 0, 0, 0);
                } else {
#pragma unroll
                    for (int ni = 0; ni < 4; ++ni)
                        acc[mi][ni] = __builtin_amdgcn_mfma_f32_16x16x32_bf16(
                            a, bfr[ni], acc[mi][ni], 0, 0, 0);
                }
            }
        }

        // kk = 1: preload ALL frags, then release the buffer and stage k0+2
        bf16x8 af1[8], bf1[4];
#pragma unroll
        for (int ni = 0; ni < 4; ++ni) bf1[ni] = *(const bf16x8*)&Bs[cur][bOff[1][ni]];
#pragma unroll
        for (int mi = 0; mi < 8; ++mi) af1[mi] = *(const bf16x8*)&As[cur][aOff[1][mi]];

        wait_lgkm0();                      // own reads of buf done
        __builtin_amdgcn_sched_barrier(0); // rule #18: pin MFMA below the wait
        __builtin_amdgcn_s_barrier();      // all waves' reads of buf done
        if (k0 + 2 < NK) stage(cur);       // overwrite just-freed buffer

#pragma unroll
        for (int mi = 0; mi < 8; ++mi) {
            if (swp) {
#pragma unroll
                for (int ni = 0; ni < 4; ++ni)
                    acc[mi][ni] = __builtin_amdgcn_mfma_f32_16x16x32_bf16(
                        bf1[ni], af1[mi], acc[mi][ni], 0, 0, 0);
            } else {
#pragma unroll
                for (int ni = 0; ni < 4; ++ni)
                    acc[mi][ni] = __builtin_amdgcn_mfma_f32_16x16x32_bf16(
                        af1[mi], bf1[ni], acc[mi][ni], 0, 0, 0);
            }
        }
    }

    if (mode == 2) {
        // NoSwap: row=token=(lane>>4)*4+reg, col=feature=lane&15
        // Vt[((b*H+h)*64+d)*S + s], 4 consecutive s per lane
        unsigned short* Co = (unsigned short*)C;
#pragma unroll
        for (int ni = 0; ni < 4; ++ni) {
            int col = n0 + wcol * 64 + ni * 16 + fr;
            float bv = bias[col];
            int hh = col >> 6, d = col & 63;
#pragma unroll
            for (int mi = 0; mi < 8; ++mi) {
                int tok = m0 + wrow * 128 + mi * 16 + kq * 4;
                int bb = tok >> 11, sbase = tok & (S_ - 1);
                uint2 pk;
                pk.x = pkbf((acc[mi][ni][0] + bv) * scl, (acc[mi][ni][1] + bv) * scl);
                pk.y = pkbf((acc[mi][ni][2] + bv) * scl, (acc[mi][ni][3] + bv) * scl);
                *(uint2*)(Co + ((size_t)((bb * H_ + hh) * 64 + d)) * S_ + sbase) = pk;
            }
        }
    } else {
        // Swap: row=token=lane&15, 4 consecutive features per lane
        unsigned short* Co = (unsigned short*)C;
#pragma unroll
        for (int ni = 0; ni < 4; ++ni) {
            int nb = n0 + wcol * 64 + ni * 16 + kq * 4;
            float4 b4 = *(const float4*)&bias[nb];
#pragma unroll
            for (int mi = 0; mi < 8; ++mi) {
                int m = m0 + wrow * 128 + mi * 16 + fr;
                uint2 pk;
                pk.x = pkbf((acc[mi][ni][0] + b4.x) * scl, (acc[mi][ni][1] + b4.y) * scl);
                pk.y = pkbf((acc[mi][ni][2] + b4.z) * scl, (acc[mi][ni][3] + b4.w) * scl);
                *(uint2*)(Co + (size_t)m * D_ + nb) = pk;
            }
        }
    }
}

// ---------------------------------------------------------------------------
// gemm_out: output projection, 128x128 tile, 4 waves (wave-tile 64x64),
// depth-3 counted-vmcnt ring. Staged = 128 MB, grid 256 = 1/CU.
// fp32 out, swapped operands (C^T frags, float4 stores).
// ---------------------------------------------------------------------------
__global__ __launch_bounds__(256, 3) void gemm_out(GemmArgs ga) {
    constexpr int NK = D_ / 32;
    const int bid = blockIdx.x;
    const int l = (bid & 7) * 32 + (bid >> 3);   // grid 256, 32/XCD
    const int bx = l & 31;
    const int by = l >> 5;

    const unsigned short* __restrict__ A = ga.A[0];
    const unsigned short* __restrict__ W = ga.W[0];
    const float* __restrict__ bias = ga.bias[0];
    float* Co = (float*)ga.C[0];

    __shared__ unsigned short As[3][8 * 512];
    __shared__ unsigned short Bs[3][8 * 512];

    const int t    = threadIdx.x;
    const int lane = t & 63;
    const int w    = t >> 6;
    const int fr   = lane & 15;
    const int kq   = lane >> 4;
    const int wrow = w >> 1, wcol = w & 1;
    const int m0 = bx * 128, n0 = by * 128;

    const int sc = lane >> 4;
    const int sr = lane & 15;

    const unsigned short* ga0 = A + (size_t)(m0 + (2 * w) * 16 + sr) * D_ + sc * 8;
    const unsigned short* ga1 = ga0 + 16 * D_;
    const unsigned short* gw0 = W + (size_t)(n0 + (2 * w) * 16 + sr) * D_ + sc * 8;
    const unsigned short* gw1 = gw0 + 16 * D_;
    const int la0 = (2 * w) * 512, la1 = (2 * w + 1) * 512;
    const int lw0 = (2 * w) * 512, lw1 = (2 * w + 1) * 512;

    int aOff[4], bOff[4];
#pragma unroll
    for (int mi = 0; mi < 4; ++mi) aOff[mi] = (wrow * 4 + mi) * 512 + (kq * 16 + fr) * 8;
#pragma unroll
    for (int ni = 0; ni < 4; ++ni) bOff[ni] = (wcol * 4 + ni) * 512 + (kq * 16 + fr) * 8;

    f32x4 acc[4][4];
#pragma unroll
    for (int i = 0; i < 4; ++i)
#pragma unroll
        for (int j = 0; j < 4; ++j) acc[i][j] = (f32x4)0.0f;

    auto stage = [&](int buf) {
        gld16(ga0, &As[buf][la0]);
        gld16(ga1, &As[buf][la1]);
        gld16(gw0, &Bs[buf][lw0]);
        gld16(gw1, &Bs[buf][lw1]);
        ga0 += 32; ga1 += 32; gw0 += 32; gw1 += 32;
    };

    stage(0);
    stage(1);
    int cur = 0;
    for (int k0 = 0; k0 < NK; ++k0) {
        __builtin_amdgcn_sched_barrier(0);
        if (k0 < NK - 1) wait_vm<4>();
        else             wait_vm<0>();
        __builtin_amdgcn_s_barrier();
        __builtin_amdgcn_sched_barrier(0);
        if (k0 + 2 < NK) {
            int pf = (cur >= 1) ? cur - 1 : cur + 2;
            stage(pf);
        }

        bf16x8 af[4], bfr[4];
#pragma unroll
        for (int mi = 0; mi < 4; ++mi) af[mi] = *(const bf16x8*)&As[cur][aOff[mi]];
#pragma unroll
        for (int ni = 0; ni < 4; ++ni) bfr[ni] = *(const bf16x8*)&Bs[cur][bOff[ni]];
#pragma unroll
        for (int mi = 0; mi < 4; ++mi)
#pragma unroll
            for (int ni = 0; ni < 4; ++ni)
                acc[mi][ni] = __builtin_amdgcn_mfma_f32_16x16x32_bf16(
                    bfr[ni], af[mi], acc[mi][ni], 0, 0, 0);
        cur = (cur < 2) ? cur + 1 : 0;
    }

    // fp32 epilogue (swapped): row=token=lane&15, 4 consecutive features
#pragma unroll
    for (int ni = 0; ni < 4; ++ni) {
        int nb = n0 + wcol * 64 + ni * 16 + kq * 4;
        float4 b4 = *(const float4*)&bias[nb];
#pragma unroll
        for (int mi = 0; mi < 4; ++mi) {
            int m = m0 + wrow * 64 + mi * 16 + fr;
            float4 o4;
            o4.x = acc[mi][ni][0] + b4.x;
            o4.y = acc[mi][ni][1] + b4.y;
            o4.z = acc[mi][ni][2] + b4.z;
            o4.w = acc[mi][ni][3] + b4.w;
            *(float4*)(Co + (size_t)m * D_ + nb) = o4;
        }
    }
}

// ---------------------------------------------------------------------------
// MFMA flash attention v7: 8 waves x 32 q-rows = 256 q-rows/block.
// Each wave owns TWO 16-row fragment columns (qc=0,1): every K/V-frag read
// feeds 2 MFMAs. Grid 256 (1/CU). Depth-3 K/V pipeline, counted vmcnt.
// XCD swizzle: XCD x -> b = x>>2, 4 heads, all 8 qt (2 MB K/V set in L2).
// LDS = 3*8K(K) + 3*8K(V) + 32K(Ps) = 80 KB.
// ---------------------------------------------------------------------------
__global__ __launch_bounds__(512, 2) void flash4(
    const unsigned short* __restrict__ Qb, const unsigned short* __restrict__ Kb,
    const unsigned short* __restrict__ Vtg, const int* __restrict__ mask,
    const int* __restrict__ flags, unsigned short* __restrict__ Xb) {
    __shared__ unsigned short Ks[3][4096];
    __shared__ unsigned short Vs[3][4096];
    __shared__ unsigned short Ps[16384];

    const int t    = threadIdx.x;
    const int lane = t & 63;
    const int w    = t >> 6;     // wave 0..7
    const int fr   = lane & 15;
    const int kq   = lane >> 4;
    const int bid = blockIdx.x;
    const int swb = ((bid & 7) << 5) | (bid >> 3);
    const int qt = swb & 7, hd = (swb >> 3) & 15, b = swb >> 7;
    const int q0 = qt * 256;
    const int swz = fr & 7;

    bf16x8 qf[2][2];
#pragma unroll
    for (int qc = 0; qc < 2; ++qc) {
        const unsigned short* qrow_p =
            Qb + (size_t)(b * S_ + q0 + w * 32 + qc * 16 + fr) * D_ + hd * 64;
        qf[qc][0] = *(const bf16x8*)(qrow_p + kq * 8);
        qf[qc][1] = *(const bf16x8*)(qrow_p + 32 + kq * 8);
    }

    unsigned int fmask[2];
#pragma unroll
    for (int qc = 0; qc < 2; ++qc) {
        int qt64 = qt * 4 + ((2 * w + qc) >> 2);
        int fl = (lane < 32) ? flags[qt64 * 32 + lane] : 0;
        fmask[qc] = (unsigned int)__ballot(fl != 0);
    }

    const unsigned short* kptr =
        Kb + (size_t)(b * S_ + (w >> 1) * 16 + fr) * D_ + hd * 64 + (w & 1) * 32 + kq * 8;
    const unsigned short* vptr =
        Vtg + ((size_t)((b * H_ + hd) * 64 + (w >> 1) * 16 + fr)) * S_ + (w & 1) * 32 + kq * 8;

    gld16(kptr, (char*)&Ks[0][0] + w * 1024);
    gld16(vptr, (char*)&Vs[0][0] + w * 1024);
    gld16(kptr + (size_t)64 * D_, (char*)&Ks[1][0] + w * 1024);
    gld16(vptr + 64,              (char*)&Vs[1][0] + w * 1024);
    const unsigned short* kpf = kptr + (size_t)128 * D_;
    const unsigned short* vpf = vptr + 128;

    unsigned short* pswr[2][4];
    const unsigned short* psrd[2][2];
#pragma unroll
    for (int qc = 0; qc < 2; ++qc) {
        int row = w * 32 + qc * 16 + fr;
#pragma unroll
        for (int mi = 0; mi < 4; ++mi) {
            int chunk = mi * 2 + (kq >> 1);
            pswr[qc][mi] = &Ps[row * 64 + ((chunk ^ swz) << 3) + ((kq & 1) << 2)];
        }
#pragma unroll
        for (int kk = 0; kk < 2; ++kk) {
            int c = kk * 4 + kq;
            psrd[qc][kk] = &Ps[row * 64 + ((c ^ swz) << 3)];
        }
    }

    const f32x4 zf = (f32x4)0.0f;
    f32x4 o[2][4];
#pragma unroll
    for (int qc = 0; qc < 2; ++qc)
#pragma unroll
        for (int i = 0; i < 4; ++i) o[qc][i] = zf;
    float2v l2[2];
    l2[0] = (float2v){0.0f, 0.0f};
    l2[1] = (float2v){0.0f, 0.0f};

    auto attn_step = [&](int cur, int kt) {
        f32x4 st[2][4];
#pragma unroll
        for (int mi = 0; mi < 4; ++mi) {
            bf16x8 a = *(const bf16x8*)&Ks[cur][mi * 1024 + (kq * 16 + fr) * 8];
            st[0][mi] = __builtin_amdgcn_mfma_f32_16x16x32_bf16(a, qf[0][0], zf, 0, 0, 0);
            st[1][mi] = __builtin_amdgcn_mfma_f32_16x16x32_bf16(a, qf[1][0], zf, 0, 0, 0);
        }
#pragma unroll
        for (int mi = 0; mi < 4; ++mi) {
            bf16x8 a = *(const bf16x8*)&Ks[cur][mi * 1024 + ((4 + kq) * 16 + fr) * 8];
            st[0][mi] = __builtin_amdgcn_mfma_f32_16x16x32_bf16(a, qf[0][1], st[0][mi], 0, 0, 0);
            st[1][mi] = __builtin_amdgcn_mfma_f32_16x16x32_bf16(a, qf[1][1], st[1][mi], 0, 0, 0);
        }

#pragma unroll
        for (int qc = 0; qc < 2; ++qc) {
            if ((fmask[qc] >> kt) & 1u) {
#pragma unroll
                for (int mi = 0; mi < 4; ++mi) {
                    int4 mv = *(const int4*)&mask[(size_t)(q0 + w * 32 + qc * 16 + fr) * S_ +
                                                  kt * 64 + mi * 16 + kq * 4];
                    if (mv.x == 0) st[qc][mi][0] = -3e8f;
                    if (mv.y == 0) st[qc][mi][1] = -3e8f;
                    if (mv.z == 0) st[qc][mi][2] = -3e8f;
                    if (mv.w == 0) st[qc][mi][3] = -3e8f;
                }
            }
        }

#pragma unroll
        for (int qc = 0; qc < 2; ++qc)
#pragma unroll
            for (int mi = 0; mi < 4; ++mi) {
                float e0 = __builtin_amdgcn_exp2f(st[qc][mi][0]);
                float e1 = __builtin_amdgcn_exp2f(st[qc][mi][1]);
                float e2 = __builtin_amdgcn_exp2f(st[qc][mi][2]);
                float e3 = __builtin_amdgcn_exp2f(st[qc][mi][3]);
                l2[qc] += (float2v){e0, e1} + (float2v){e2, e3};
                uint2 pk;
                pk.x = pkbf(e0, e1);
                pk.y = pkbf(e2, e3);
                *(uint2*)pswr[qc][mi] = pk;
            }

#pragma unroll
        for (int kk = 0; kk < 2; ++kk) {
            bf16x8 pb0 = *(const bf16x8*)psrd[0][kk];
            bf16x8 pb1 = *(const bf16x8*)psrd[1][kk];
#pragma unroll
            for (int mi = 0; mi < 4; ++mi) {
                bf16x8 a = *(const bf16x8*)&Vs[cur][mi * 1024 + ((kk * 4 + kq) * 16 + fr) * 8];
                o[0][mi] = __builtin_amdgcn_mfma_f32_16x16x32_bf16(a, pb0, o[0][mi], 0, 0, 0);
                o[1][mi] = __builtin_amdgcn_mfma_f32_16x16x32_bf16(a, pb1, o[1][mi], 0, 0, 0);
            }
        }
    };

    int cur = 0;
    for (int kt = 0; kt < 31; ++kt) {
        __builtin_amdgcn_sched_barrier(0);
        wait_vm<2>();
        __builtin_amdgcn_s_barrier();
        __builtin_amdgcn_sched_barrier(0);
        if (kt < 30) {
            int pf = (cur >= 1) ? cur - 1 : cur + 2;
            gld16(kpf, (char*)&Ks[pf][0] + w * 1024);
            gld16(vpf, (char*)&Vs[pf][0] + w * 1024);
            kpf += (size_t)64 * D_;
            vpf += 64;
        }
        attn_step(cur, kt);
        cur = (cur < 2) ? cur + 1 : 0;
    }
    __builtin_amdgcn_sched_barrier(0);
    wait_vm<0>();
    __builtin_amdgcn_s_barrier();
    __builtin_amdgcn_sched_barrier(0);
    attn_step(cur, 31);

#pragma unroll
    for (int qc = 0; qc < 2; ++qc) {
        float l_i = l2[qc].x + l2[qc].y;
        l_i += __shfl_xor(l_i, 16, 64);
        l_i += __shfl_xor(l_i, 32, 64);
        float rl = 1.0f / l_i;
#pragma unroll
        for (int mi = 0; mi < 4; ++mi) {
            uint2 pk;
            pk.x = pkbf(o[qc][mi][0] * rl, o[qc][mi][1] * rl);
            pk.y = pkbf(o[qc][mi][2] * rl, o[qc][mi][3] * rl);
            *(uint2*)(Xb + (size_t)(b * S_ + q0 + w * 32 + qc * 16 + fr) * D_ +
                      hd * 64 + mi * 16 + kq * 4) = pk;
        }
    }
}

// ---------------------------------------------------------------------------
extern "C" void kernel_launch(void* const* d_in, const int* in_sizes, int n_in,
                              void* d_out, int out_size, void* d_ws, size_t ws_size,
                              hipStream_t stream) {
    const float* q    = (const float*)d_in[0];
    const float* k    = (const float*)d_in[1];
    const float* v    = (const float*)d_in[2];
    const int*   mask = (const int*)d_in[3];
    const float* Wq   = (const float*)d_in[4];
    const float* bq   = (const float*)d_in[5];
    const float* Wk   = (const float*)d_in[6];
    const float* bk   = (const float*)d_in[7];
    const float* Wv   = (const float*)d_in[8];
    const float* bv   = (const float*)d_in[9];
    const float* Wo   = (const float*)d_in[10];
    const float* bo   = (const float*)d_in[11];
    float* out = (float*)d_out;

    // workspace (shorts): qb kb vb | Qf Kf Vt | wqb wkb wvb wob | flags  (~59 MB)
    unsigned short* qb  = (unsigned short*)d_ws;
    unsigned short* kb  = qb + QN;
    unsigned short* vb  = kb + QN;
    unsigned short* Qf  = vb + QN;
    unsigned short* Kf  = Qf + QN;
    unsigned short* Vt  = Kf + QN;
    unsigned short* wqb = Vt + QN;
    unsigned short* wkb = wqb + WN;
    unsigned short* wvb = wkb + WN;
    unsigned short* wob = wvb + WN;
    int* flags = (int*)(wob + WN);

    const float SC = 0.18033688011112042f;  // (1/8) * log2(e)

    prep_kernel<<<9216, 256, 0, stream>>>(q, k, v, Wq, Wk, Wv, Wo, mask,
                                          qb, kb, vb, wqb, wkb, wvb, wob, flags);

    GemmArgs g1;
    g1.A[0] = qb;  g1.W[0] = wqb; g1.bias[0] = bq; g1.C[0] = Qf; g1.mode[0] = 1; g1.scale[0] = SC;
    g1.A[1] = kb;  g1.W[1] = wkb; g1.bias[1] = bk; g1.C[1] = Kf; g1.mode[1] = 1; g1.scale[1] = 1.0f;
    g1.A[2] = vb;  g1.W[2] = wvb; g1.bias[2] = bv; g1.C[2] = Vt; g1.mode[2] = 2; g1.scale[2] = 1.0f;
    gemm_qkv<<<192, 512, 0, stream>>>(g1);

    flash4<<<256, 512, 0, stream>>>(Qf, Kf, Vt, mask, flags, Qf);

    GemmArgs g2;
    g2.A[0] = Qf; g2.W[0] = wob; g2.bias[0] = bo; g2.C[0] = out; g2.mode[0] = 0; g2.scale[0] = 1.0f;
    g2.A[1] = g2.A[2] = nullptr; g2.W[1] = g2.W[2] = nullptr;
    g2.bias[1] = g2.bias[2] = nullptr; g2.C[1] = g2.C[2] = nullptr;
    g2.mode[1] = g2.mode[2] = 0; g2.scale[1] = g2.scale[2] = 1.0f;
    gemm_out<<<256, 256, 0, stream>>>(g2);
}

// Round 9
// 299.271 us; speedup vs baseline: 1.0388x; 1.0388x over previous
//
#include <hip/hip_runtime.h>
#include <hip/hip_bf16.h>
#include <stdint.h>

// Problem constants
#define B_    2
#define S_    2048
#define D_    1024
#define H_    16
#define NTOK  (B_ * S_)   // 4096

typedef __attribute__((ext_vector_type(8))) short bf16x8;
typedef __attribute__((ext_vector_type(4))) float f32x4;
typedef __attribute__((ext_vector_type(2))) float float2v;
typedef __attribute__((ext_vector_type(2))) __bf16 bfv2;

// packed pair fp32 -> 2x bf16 (v_cvt_pk_bf16_f32, RNE)
static __device__ __forceinline__ unsigned int pkbf(float a, float b) {
    float2v fv = {a, b};
    bfv2 r = __builtin_convertvector(fv, bfv2);
    unsigned int u;
    __builtin_memcpy(&u, &r, 4);
    return u;
}

// async global->LDS, 16 B per lane; LDS dest = wave-uniform base + lane*16
using g_cu32 = __attribute__((address_space(1))) const unsigned int;
using l_u32  = __attribute__((address_space(3))) unsigned int;
static __device__ __forceinline__ void gld16(const void* g, void* l) {
    __builtin_amdgcn_global_load_lds((g_cu32*)g, (l_u32*)l, 16, 0, 0);
}

// counted vmcnt wait (T4)
template<int N> static __device__ __forceinline__ void wait_vm() {
    if constexpr (N == 0)      asm volatile("s_waitcnt vmcnt(0)" ::: "memory");
    else if constexpr (N == 4) asm volatile("s_waitcnt vmcnt(4)" ::: "memory");
}

#define QN ((size_t)NTOK * D_)   // 4194304
#define WN ((size_t)D_ * D_)     // 1048576 = 1<<20

struct SwapT { static constexpr bool value = true; };
struct NoSwapT { static constexpr bool value = false; };

// ---------------------------------------------------------------------------
// prep: blocks [0,8192) = fp32->bf16 bulk convert (q,k,v + 4 weights);
//       blocks [8192,9216) = mask tile flags (flags[qt][kt] = any-zero in 64x64).
// ---------------------------------------------------------------------------
__global__ __launch_bounds__(256) void prep_kernel(
    const float* __restrict__ q, const float* __restrict__ k, const float* __restrict__ v,
    const float* __restrict__ Wq, const float* __restrict__ Wk,
    const float* __restrict__ Wv, const float* __restrict__ Wo,
    const int* __restrict__ mask,
    unsigned short* __restrict__ qb, unsigned short* __restrict__ kb,
    unsigned short* __restrict__ vb, unsigned short* __restrict__ wqb,
    unsigned short* __restrict__ wkb, unsigned short* __restrict__ wvb,
    unsigned short* __restrict__ wob, int* __restrict__ flags) {
    __shared__ int anyz;
    if (blockIdx.x < 8192) {
        size_t i = ((size_t)blockIdx.x * 256 + threadIdx.x) * 8;
        const float* s; unsigned short* d; size_t off;
        if (i < QN)          { s = q; d = qb; off = i; }
        else if (i < 2 * QN) { s = k; d = kb; off = i - QN; }
        else if (i < 3 * QN) { s = v; d = vb; off = i - 2 * QN; }
        else {
            size_t j = i - 3 * QN;
            int wi = (int)(j >> 20);
            s = (wi == 0) ? Wq : (wi == 1) ? Wk : (wi == 2) ? Wv : Wo;
            d = (wi == 0) ? wqb : (wi == 1) ? wkb : (wi == 2) ? wvb : wob;
            off = j & (WN - 1);
        }
        float4 a = *(const float4*)(s + off);
        float4 b = *(const float4*)(s + off + 4);
        uint4 pk;
        pk.x = pkbf(a.x, a.y); pk.y = pkbf(a.z, a.w);
        pk.z = pkbf(b.x, b.y); pk.w = pkbf(b.z, b.w);
        *(uint4*)(d + off) = pk;
    } else {
        if (threadIdx.x == 0) anyz = 0;
        __syncthreads();
        int bid2 = blockIdx.x - 8192;
        const int qt = bid2 >> 5, kt = bid2 & 31;
        int az = 0;
        for (int i = threadIdx.x; i < 64 * 64; i += 256) {
            int r = i >> 6, c = i & 63;
            az |= (mask[(size_t)(qt * 64 + r) * S_ + kt * 64 + c] == 0) ? 1 : 0;
        }
        if (az) atomicOr(&anyz, 1);
        __syncthreads();
        if (threadIdx.x == 0) flags[qt * 32 + kt] = anyz;
    }
}

// ---------------------------------------------------------------------------
// gemm_async: QKV projections. EXACT REVERT to the R3 best (57.7 us):
// 128x128 tile, BK=32, 256 thr = 4 waves (2x2, wave-tile 64x64), plain 3-D
// grid, depth-3 counted-vmcnt ring (raw s_barrier, no drain in main loop).
// R8's 256x256 attempt spilled to scratch (WRITE_SIZE 2x, 99 us) - reverted.
// modes: 1 = bf16 out (Swap: acc = C^T frags), 2 = bf16 Vt layout (NoSwap).
// ---------------------------------------------------------------------------
struct GemmArgs {
    const unsigned short* A[3];
    const unsigned short* W[3];
    const float* bias[3];
    void* C[3];
    int mode[3];
    float scale[3];
};

__global__ __launch_bounds__(256, 3) void gemm_async(GemmArgs ga) {
    constexpr int NK = D_ / 32;    // 32 k-steps
    const int z = blockIdx.z;
    const unsigned short* __restrict__ A = ga.A[z];
    const unsigned short* __restrict__ W = ga.W[z];
    const float* __restrict__ bias = ga.bias[z];
    void* C = ga.C[z];
    const int mode = ga.mode[z];
    const float scl = ga.scale[z];

    __shared__ unsigned short As[3][8 * 512];
    __shared__ unsigned short Bs[3][8 * 512];

    const int t    = threadIdx.x;
    const int lane = t & 63;
    const int w    = t >> 6;
    const int fr   = lane & 15;
    const int kq   = lane >> 4;
    const int wrow = w >> 1, wcol = w & 1;
    const int m0 = blockIdx.x * 128, n0 = blockIdx.y * 128;

    const int sc = lane >> 4;   // chunk
    const int sr = lane & 15;   // row in group

    const unsigned short* ga0 = A + (size_t)(m0 + (2 * w) * 16 + sr) * D_ + sc * 8;
    const unsigned short* ga1 = ga0 + 16 * D_;
    const unsigned short* gw0 = W + (size_t)(n0 + (2 * w) * 16 + sr) * D_ + sc * 8;
    const unsigned short* gw1 = gw0 + 16 * D_;
    const int la0 = (2 * w) * 512, la1 = (2 * w + 1) * 512;
    const int lw0 = (2 * w) * 512, lw1 = (2 * w + 1) * 512;

    int aOff[4], bOff[4];
#pragma unroll
    for (int mi = 0; mi < 4; ++mi) aOff[mi] = (wrow * 4 + mi) * 512 + (kq * 16 + fr) * 8;
#pragma unroll
    for (int ni = 0; ni < 4; ++ni) bOff[ni] = (wcol * 4 + ni) * 512 + (kq * 16 + fr) * 8;

    f32x4 acc[4][4];
#pragma unroll
    for (int i = 0; i < 4; ++i)
#pragma unroll
        for (int j = 0; j < 4; ++j) acc[i][j] = (f32x4)0.0f;

    auto stage = [&](int buf) {
        gld16(ga0, &As[buf][la0]);
        gld16(ga1, &As[buf][la1]);
        gld16(gw0, &Bs[buf][lw0]);
        gld16(gw1, &Bs[buf][lw1]);
        ga0 += 32; ga1 += 32; gw0 += 32; gw1 += 32;
    };

    auto kloop = [&](auto swc) {
        constexpr bool SW = decltype(swc)::value;
        auto mma_step = [&](int cur) {
            bf16x8 af[4], bfr[4];
#pragma unroll
            for (int mi = 0; mi < 4; ++mi) af[mi] = *(const bf16x8*)&As[cur][aOff[mi]];
#pragma unroll
            for (int ni = 0; ni < 4; ++ni) bfr[ni] = *(const bf16x8*)&Bs[cur][bOff[ni]];
#pragma unroll
            for (int mi = 0; mi < 4; ++mi)
#pragma unroll
                for (int ni = 0; ni < 4; ++ni) {
                    if constexpr (SW)
                        acc[mi][ni] = __builtin_amdgcn_mfma_f32_16x16x32_bf16(
                            bfr[ni], af[mi], acc[mi][ni], 0, 0, 0);
                    else
                        acc[mi][ni] = __builtin_amdgcn_mfma_f32_16x16x32_bf16(
                            af[mi], bfr[ni], acc[mi][ni], 0, 0, 0);
                }
        };

        stage(0);
        stage(1);
        int cur = 0;
        for (int k0 = 0; k0 < NK - 1; ++k0) {
            __builtin_amdgcn_sched_barrier(0);
            wait_vm<4>();                         // tile k0 resident (own loads)
            __builtin_amdgcn_s_barrier();         // ... for all waves
            __builtin_amdgcn_sched_barrier(0);
            if (k0 + 2 < NK) {
                int pf = (cur >= 1) ? cur - 1 : cur + 2;   // (cur+2)%3
                stage(pf);
            }
            mma_step(cur);
            cur = (cur < 2) ? cur + 1 : 0;
        }
        __builtin_amdgcn_sched_barrier(0);
        wait_vm<0>();                             // final tile: full drain
        __builtin_amdgcn_s_barrier();
        __builtin_amdgcn_sched_barrier(0);
        mma_step(cur);
    };
    if (mode == 2) kloop(NoSwapT{}); else kloop(SwapT{});

    if (mode == 2) {
        // NoSwap: row=token=(lane>>4)*4+reg, col=feature=lane&15
        // Vt[((b*H+h)*64+d)*S + s], 4 consecutive s per lane
        unsigned short* Co = (unsigned short*)C;
#pragma unroll
        for (int ni = 0; ni < 4; ++ni) {
            int col = n0 + wcol * 64 + ni * 16 + fr;
            float bv = bias[col];
            int hh = col >> 6, d = col & 63;
#pragma unroll
            for (int mi = 0; mi < 4; ++mi) {
                int tok = m0 + wrow * 64 + mi * 16 + kq * 4;
                int bb = tok >> 11, sbase = tok & (S_ - 1);
                uint2 pk;
                pk.x = pkbf((acc[mi][ni][0] + bv) * scl, (acc[mi][ni][1] + bv) * scl);
                pk.y = pkbf((acc[mi][ni][2] + bv) * scl, (acc[mi][ni][3] + bv) * scl);
                *(uint2*)(Co + ((size_t)((bb * H_ + hh) * 64 + d)) * S_ + sbase) = pk;
            }
        }
    } else {
        // Swap: row=token=lane&15, 4 consecutive features per lane
        unsigned short* Co = (unsigned short*)C;
#pragma unroll
        for (int ni = 0; ni < 4; ++ni) {
            int nb = n0 + wcol * 64 + ni * 16 + kq * 4;
            float4 b4 = *(const float4*)&bias[nb];
#pragma unroll
            for (int mi = 0; mi < 4; ++mi) {
                int m = m0 + wrow * 64 + mi * 16 + fr;
                uint2 pk;
                pk.x = pkbf((acc[mi][ni][0] + b4.x) * scl, (acc[mi][ni][1] + b4.y) * scl);
                pk.y = pkbf((acc[mi][ni][2] + b4.z) * scl, (acc[mi][ni][3] + b4.w) * scl);
                *(uint2*)(Co + (size_t)m * D_ + nb) = pk;
            }
        }
    }
}

// ---------------------------------------------------------------------------
// gemm_out: output projection, 128x128 tile, 4 waves (wave-tile 64x64),
// depth-3 counted-vmcnt ring, grid 256 (1/CU), XCD-chunked. Staged 128 MB.
// fp32 out, swapped operands (C^T frags, float4 stores). Proven in R7/R8.
// ---------------------------------------------------------------------------
__global__ __launch_bounds__(256, 3) void gemm_out(GemmArgs ga) {
    constexpr int NK = D_ / 32;
    const int bid = blockIdx.x;
    const int l = (bid & 7) * 32 + (bid >> 3);   // grid 256, 32/XCD
    const int bx = l & 31;
    const int by = l >> 5;

    const unsigned short* __restrict__ A = ga.A[0];
    const unsigned short* __restrict__ W = ga.W[0];
    const float* __restrict__ bias = ga.bias[0];
    float* Co = (float*)ga.C[0];

    __shared__ unsigned short As[3][8 * 512];
    __shared__ unsigned short Bs[3][8 * 512];

    const int t    = threadIdx.x;
    const int lane = t & 63;
    const int w    = t >> 6;
    const int fr   = lane & 15;
    const int kq   = lane >> 4;
    const int wrow = w >> 1, wcol = w & 1;
    const int m0 = bx * 128, n0 = by * 128;

    const int sc = lane >> 4;
    const int sr = lane & 15;

    const unsigned short* ga0 = A + (size_t)(m0 + (2 * w) * 16 + sr) * D_ + sc * 8;
    const unsigned short* ga1 = ga0 + 16 * D_;
    const unsigned short* gw0 = W + (size_t)(n0 + (2 * w) * 16 + sr) * D_ + sc * 8;
    const unsigned short* gw1 = gw0 + 16 * D_;
    const int la0 = (2 * w) * 512, la1 = (2 * w + 1) * 512;
    const int lw0 = (2 * w) * 512, lw1 = (2 * w + 1) * 512;

    int aOff[4], bOff[4];
#pragma unroll
    for (int mi = 0; mi < 4; ++mi) aOff[mi] = (wrow * 4 + mi) * 512 + (kq * 16 + fr) * 8;
#pragma unroll
    for (int ni = 0; ni < 4; ++ni) bOff[ni] = (wcol * 4 + ni) * 512 + (kq * 16 + fr) * 8;

    f32x4 acc[4][4];
#pragma unroll
    for (int i = 0; i < 4; ++i)
#pragma unroll
        for (int j = 0; j < 4; ++j) acc[i][j] = (f32x4)0.0f;

    auto stage = [&](int buf) {
        gld16(ga0, &As[buf][la0]);
        gld16(ga1, &As[buf][la1]);
        gld16(gw0, &Bs[buf][lw0]);
        gld16(gw1, &Bs[buf][lw1]);
        ga0 += 32; ga1 += 32; gw0 += 32; gw1 += 32;
    };

    stage(0);
    stage(1);
    int cur = 0;
    for (int k0 = 0; k0 < NK; ++k0) {
        __builtin_amdgcn_sched_barrier(0);
        if (k0 < NK - 1) wait_vm<4>();
        else             wait_vm<0>();
        __builtin_amdgcn_s_barrier();
        __builtin_amdgcn_sched_barrier(0);
        if (k0 + 2 < NK) {
            int pf = (cur >= 1) ? cur - 1 : cur + 2;
            stage(pf);
        }

        bf16x8 af[4], bfr[4];
#pragma unroll
        for (int mi = 0; mi < 4; ++mi) af[mi] = *(const bf16x8*)&As[cur][aOff[mi]];
#pragma unroll
        for (int ni = 0; ni < 4; ++ni) bfr[ni] = *(const bf16x8*)&Bs[cur][bOff[ni]];
#pragma unroll
        for (int mi = 0; mi < 4; ++mi)
#pragma unroll
            for (int ni = 0; ni < 4; ++ni)
                acc[mi][ni] = __builtin_amdgcn_mfma_f32_16x16x32_bf16(
                    bfr[ni], af[mi], acc[mi][ni], 0, 0, 0);
        cur = (cur < 2) ? cur + 1 : 0;
    }

    // fp32 epilogue (swapped): row=token=lane&15, 4 consecutive features
#pragma unroll
    for (int ni = 0; ni < 4; ++ni) {
        int nb = n0 + wcol * 64 + ni * 16 + kq * 4;
        float4 b4 = *(const float4*)&bias[nb];
#pragma unroll
        for (int mi = 0; mi < 4; ++mi) {
            int m = m0 + wrow * 64 + mi * 16 + fr;
            float4 o4;
            o4.x = acc[mi][ni][0] + b4.x;
            o4.y = acc[mi][ni][1] + b4.y;
            o4.z = acc[mi][ni][2] + b4.z;
            o4.w = acc[mi][ni][3] + b4.w;
            *(float4*)(Co + (size_t)m * D_ + nb) = o4;
        }
    }
}

// ---------------------------------------------------------------------------
// MFMA flash attention v8: dual-q-column at 2 blocks/CU.
// 4 waves (256 thr) x 32 q-rows = 128 q-rows/block; wave w owns rows
// [w*32, w*32+32) as two 16-row fragment columns (qc=0,1) -> every K/V-frag
// read feeds 2 MFMAs: 20 ds_read_b128 per wave-step for 32 MFMA (v6 was
// 18 for 16). Grid 512 = 2 blocks/CU (v7's regression was 1 block/CU: no
// cross-block overlap). Per-CU LDS read traffic per step: 288 -> 160 KB.
// Depth-3 K/V pipeline, counted vmcnt(4) (4 gld16/wave/tile: K h0,h1 + V
// h0,h1). LDS = 3*8K(K) + 3*8K(V) + 16K(Ps) = 64 KB -> 2 blocks/CU.
// XCD-chunked bid swizzle (v6 mapping).
// ---------------------------------------------------------------------------
__global__ __launch_bounds__(256, 2) void flash4(
    const unsigned short* __restrict__ Qb, const unsigned short* __restrict__ Kb,
    const unsigned short* __restrict__ Vtg, const int* __restrict__ mask,
    const int* __restrict__ flags, unsigned short* __restrict__ Xb) {
    __shared__ unsigned short Ks[3][4096];
    __shared__ unsigned short Vs[3][4096];
    __shared__ unsigned short Ps[8192];

    const int t    = threadIdx.x;
    const int lane = t & 63;
    const int w    = t >> 6;     // wave 0..3
    const int fr   = lane & 15;
    const int kq   = lane >> 4;
    // XCD-chunked swizzle (nwg=512, 64/XCD)
    const int bid = blockIdx.x;
    const int swb = ((bid & 7) << 6) | (bid >> 3);
    const int qt = swb & 15, hd = (swb >> 4) & 15, b = swb >> 8;
    const int q0 = qt * 128;
    const int swz = fr & 7;

    // Q B-frags for both 16-row columns
    bf16x8 qf[2][2];
#pragma unroll
    for (int qc = 0; qc < 2; ++qc) {
        const unsigned short* qrow_p =
            Qb + (size_t)(b * S_ + q0 + w * 32 + qc * 16 + fr) * D_ + hd * 64;
        qf[qc][0] = *(const bf16x8*)(qrow_p + kq * 8);
        qf[qc][1] = *(const bf16x8*)(qrow_p + 32 + kq * 8);
    }

    // per-(wave,qc) mask-tile flags; 64-row tile = qt*2 + ((2w+qc)>>1)
    unsigned int fmask[2];
#pragma unroll
    for (int qc = 0; qc < 2; ++qc) {
        int qt64 = qt * 2 + ((2 * w + qc) >> 1);
        int fl = (lane < 32) ? flags[qt64 * 32 + lane] : 0;
        fmask[qc] = (unsigned int)__ballot(fl != 0);
    }

    // staging: wave w owns key-group / d-group w (16 rows), both 32-halves.
    // K dest bytes: w*2048 (+1024 for half 1); same for V.
    const unsigned short* kp0 =
        Kb + (size_t)(b * S_ + w * 16 + fr) * D_ + hd * 64 + kq * 8;
    const unsigned short* vp0 =
        Vtg + ((size_t)((b * H_ + hd) * 64 + w * 16 + fr)) * S_ + kq * 8;

    auto stageKV = [&](int buf, const unsigned short* kp, const unsigned short* vp) {
        gld16(kp,      (char*)&Ks[buf][0] + w * 2048);
        gld16(kp + 32, (char*)&Ks[buf][0] + w * 2048 + 1024);
        gld16(vp,      (char*)&Vs[buf][0] + w * 2048);
        gld16(vp + 32, (char*)&Vs[buf][0] + w * 2048 + 1024);
    };

    // prologue: tiles 0,1 into bufs 0,1
    stageKV(0, kp0, vp0);
    stageKV(1, kp0 + (size_t)64 * D_, vp0 + 64);
    const unsigned short* kpf = kp0 + (size_t)128 * D_;
    const unsigned short* vpf = vp0 + 128;

    // hoisted Ps write/read addresses; row = w*32 + qc*16 + fr  (128 rows)
    unsigned short* pswr[2][4];
    const unsigned short* psrd[2][2];
#pragma unroll
    for (int qc = 0; qc < 2; ++qc) {
        int row = w * 32 + qc * 16 + fr;
#pragma unroll
        for (int mi = 0; mi < 4; ++mi) {
            int chunk = mi * 2 + (kq >> 1);
            pswr[qc][mi] = &Ps[row * 64 + ((chunk ^ swz) << 3) + ((kq & 1) << 2)];
        }
#pragma unroll
        for (int kk = 0; kk < 2; ++kk) {
            int c = kk * 4 + kq;
            psrd[qc][kk] = &Ps[row * 64 + ((c ^ swz) << 3)];
        }
    }

    const f32x4 zf = (f32x4)0.0f;
    f32x4 o[2][4];
#pragma unroll
    for (int qc = 0; qc < 2; ++qc)
#pragma unroll
        for (int i = 0; i < 4; ++i) o[qc][i] = zf;
    float2v l2[2];
    l2[0] = (float2v){0.0f, 0.0f};
    l2[1] = (float2v){0.0f, 0.0f};

    auto attn_step = [&](int cur, int kt) {
        // S^T = K . Q^T; each K-frag feeds both q-columns.
        f32x4 st[2][4];
#pragma unroll
        for (int mi = 0; mi < 4; ++mi) {
            bf16x8 a = *(const bf16x8*)&Ks[cur][mi * 1024 + (kq * 16 + fr) * 8];
            st[0][mi] = __builtin_amdgcn_mfma_f32_16x16x32_bf16(a, qf[0][0], zf, 0, 0, 0);
            st[1][mi] = __builtin_amdgcn_mfma_f32_16x16x32_bf16(a, qf[1][0], zf, 0, 0, 0);
        }
#pragma unroll
        for (int mi = 0; mi < 4; ++mi) {
            bf16x8 a = *(const bf16x8*)&Ks[cur][mi * 1024 + ((4 + kq) * 16 + fr) * 8];
            st[0][mi] = __builtin_amdgcn_mfma_f32_16x16x32_bf16(a, qf[0][1], st[0][mi], 0, 0, 0);
            st[1][mi] = __builtin_amdgcn_mfma_f32_16x16x32_bf16(a, qf[1][1], st[1][mi], 0, 0, 0);
        }

#pragma unroll
        for (int qc = 0; qc < 2; ++qc) {
            if ((fmask[qc] >> kt) & 1u) {
#pragma unroll
                for (int mi = 0; mi < 4; ++mi) {
                    int4 mv = *(const int4*)&mask[(size_t)(q0 + w * 32 + qc * 16 + fr) * S_ +
                                                  kt * 64 + mi * 16 + kq * 4];
                    if (mv.x == 0) st[qc][mi][0] = -3e8f;
                    if (mv.y == 0) st[qc][mi][1] = -3e8f;
                    if (mv.z == 0) st[qc][mi][2] = -3e8f;
                    if (mv.w == 0) st[qc][mi][3] = -3e8f;
                }
            }
        }

        // P = exp2(s), accumulate l, pack bf16 into swizzled Ps
#pragma unroll
        for (int qc = 0; qc < 2; ++qc)
#pragma unroll
            for (int mi = 0; mi < 4; ++mi) {
                float e0 = __builtin_amdgcn_exp2f(st[qc][mi][0]);
                float e1 = __builtin_amdgcn_exp2f(st[qc][mi][1]);
                float e2 = __builtin_amdgcn_exp2f(st[qc][mi][2]);
                float e3 = __builtin_amdgcn_exp2f(st[qc][mi][3]);
                l2[qc] += (float2v){e0, e1} + (float2v){e2, e3};
                uint2 pk;
                pk.x = pkbf(e0, e1);
                pk.y = pkbf(e2, e3);
                *(uint2*)pswr[qc][mi] = pk;
            }

        // O^T += Vt . P^T; each V-frag feeds both q-columns.
#pragma unroll
        for (int kk = 0; kk < 2; ++kk) {
            bf16x8 pb0 = *(const bf16x8*)psrd[0][kk];
            bf16x8 pb1 = *(const bf16x8*)psrd[1][kk];
#pragma unroll
            for (int mi = 0; mi < 4; ++mi) {
                bf16x8 a = *(const bf16x8*)&Vs[cur][mi * 1024 + ((kk * 4 + kq) * 16 + fr) * 8];
                o[0][mi] = __builtin_amdgcn_mfma_f32_16x16x32_bf16(a, pb0, o[0][mi], 0, 0, 0);
                o[1][mi] = __builtin_amdgcn_mfma_f32_16x16x32_bf16(a, pb1, o[1][mi], 0, 0, 0);
            }
        }
    };

    int cur = 0;
    for (int kt = 0; kt < 31; ++kt) {
        __builtin_amdgcn_sched_barrier(0);
        wait_vm<4>();                       // tile kt resident (own 4 loads)
        __builtin_amdgcn_s_barrier();       // ... for all waves
        __builtin_amdgcn_sched_barrier(0);
        if (kt < 30) {
            int pf = (cur >= 1) ? cur - 1 : cur + 2;   // (cur+2)%3
            stageKV(pf, kpf, vpf);
            kpf += (size_t)64 * D_;
            vpf += 64;
        }
        attn_step(cur, kt);
        cur = (cur < 2) ? cur + 1 : 0;
    }
    __builtin_amdgcn_sched_barrier(0);
    wait_vm<0>();                           // last tile: full drain
    __builtin_amdgcn_s_barrier();
    __builtin_amdgcn_sched_barrier(0);
    attn_step(cur, 31);

    // final l reduction + X write per q-column
#pragma unroll
    for (int qc = 0; qc < 2; ++qc) {
        float l_i = l2[qc].x + l2[qc].y;
        l_i += __shfl_xor(l_i, 16, 64);
        l_i += __shfl_xor(l_i, 32, 64);
        float rl = 1.0f / l_i;
#pragma unroll
        for (int mi = 0; mi < 4; ++mi) {
            uint2 pk;
            pk.x = pkbf(o[qc][mi][0] * rl, o[qc][mi][1] * rl);
            pk.y = pkbf(o[qc][mi][2] * rl, o[qc][mi][3] * rl);
            *(uint2*)(Xb + (size_t)(b * S_ + q0 + w * 32 + qc * 16 + fr) * D_ +
                      hd * 64 + mi * 16 + kq * 4) = pk;
        }
    }
}

// ---------------------------------------------------------------------------
extern "C" void kernel_launch(void* const* d_in, const int* in_sizes, int n_in,
                              void* d_out, int out_size, void* d_ws, size_t ws_size,
                              hipStream_t stream) {
    const float* q    = (const float*)d_in[0];
    const float* k    = (const float*)d_in[1];
    const float* v    = (const float*)d_in[2];
    const int*   mask = (const int*)d_in[3];
    const float* Wq   = (const float*)d_in[4];
    const float* bq   = (const float*)d_in[5];
    const float* Wk   = (const float*)d_in[6];
    const float* bk   = (const float*)d_in[7];
    const float* Wv   = (const float*)d_in[8];
    const float* bv   = (const float*)d_in[9];
    const float* Wo   = (const float*)d_in[10];
    const float* bo   = (const float*)d_in[11];
    float* out = (float*)d_out;

    // workspace (shorts): qb kb vb | Qf Kf Vt | wqb wkb wvb wob | flags  (~59 MB)
    unsigned short* qb  = (unsigned short*)d_ws;
    unsigned short* kb  = qb + QN;
    unsigned short* vb  = kb + QN;
    unsigned short* Qf  = vb + QN;
    unsigned short* Kf  = Qf + QN;
    unsigned short* Vt  = Kf + QN;
    unsigned short* wqb = Vt + QN;
    unsigned short* wkb = wqb + WN;
    unsigned short* wvb = wkb + WN;
    unsigned short* wob = wvb + WN;
    int* flags = (int*)(wob + WN);

    const float SC = 0.18033688011112042f;  // (1/8) * log2(e)

    prep_kernel<<<9216, 256, 0, stream>>>(q, k, v, Wq, Wk, Wv, Wo, mask,
                                          qb, kb, vb, wqb, wkb, wvb, wob, flags);

    GemmArgs g1;
    g1.A[0] = qb;  g1.W[0] = wqb; g1.bias[0] = bq; g1.C[0] = Qf; g1.mode[0] = 1; g1.scale[0] = SC;
    g1.A[1] = kb;  g1.W[1] = wkb; g1.bias[1] = bk; g1.C[1] = Kf; g1.mode[1] = 1; g1.scale[1] = 1.0f;
    g1.A[2] = vb;  g1.W[2] = wvb; g1.bias[2] = bv; g1.C[2] = Vt; g1.mode[2] = 2; g1.scale[2] = 1.0f;
    gemm_async<<<dim3(NTOK / 128, D_ / 128, 3), 256, 0, stream>>>(g1);

    flash4<<<512, 256, 0, stream>>>(Qf, Kf, Vt, mask, flags, Qf);

    GemmArgs g2;
    g2.A[0] = Qf; g2.W[0] = wob; g2.bias[0] = bo; g2.C[0] = out; g2.mode[0] = 0; g2.scale[0] = 1.0f;
    g2.A[1] = g2.A[2] = nullptr; g2.W[1] = g2.W[2] = nullptr;
    g2.bias[1] = g2.bias[2] = nullptr; g2.C[1] = g2.C[2] = nullptr;
    g2.mode[1] = g2.mode[2] = 0; g2.scale[1] = g2.scale[2] = 1.0f;
    gemm_out<<<256, 256, 0, stream>>>(g2);
}

// Round 10
// 261.116 us; speedup vs baseline: 1.1906x; 1.1461x over previous
//
#include <hip/hip_runtime.h>
#include <hip/hip_bf16.h>
#include <stdint.h>

// Problem constants
#define B_    2
#define S_    2048
#define D_    1024
#define H_    16
#define NTOK  (B_ * S_)   // 4096

typedef __attribute__((ext_vector_type(8))) short bf16x8;
typedef __attribute__((ext_vector_type(4))) float f32x4;
typedef __attribute__((ext_vector_type(2))) float float2v;
typedef __attribute__((ext_vector_type(2))) __bf16 bfv2;

// packed pair fp32 -> 2x bf16 (v_cvt_pk_bf16_f32, RNE)
static __device__ __forceinline__ unsigned int pkbf(float a, float b) {
    float2v fv = {a, b};
    bfv2 r = __builtin_convertvector(fv, bfv2);
    unsigned int u;
    __builtin_memcpy(&u, &r, 4);
    return u;
}

// async global->LDS, 16 B per lane; LDS dest = wave-uniform base + lane*16
using g_cu32 = __attribute__((address_space(1))) const unsigned int;
using l_u32  = __attribute__((address_space(3))) unsigned int;
static __device__ __forceinline__ void gld16(const void* g, void* l) {
    __builtin_amdgcn_global_load_lds((g_cu32*)g, (l_u32*)l, 16, 0, 0);
}

// counted vmcnt wait (T4): lets prefetched global_load_lds stay in flight
// across raw s_barrier (no __syncthreads drain).
template<int N> static __device__ __forceinline__ void wait_vm() {
    if constexpr (N == 0)      asm volatile("s_waitcnt vmcnt(0)" ::: "memory");
    else if constexpr (N == 2) asm volatile("s_waitcnt vmcnt(2)" ::: "memory");
    else if constexpr (N == 3) asm volatile("s_waitcnt vmcnt(3)" ::: "memory");
    else if constexpr (N == 4) asm volatile("s_waitcnt vmcnt(4)" ::: "memory");
}

#define QN ((size_t)NTOK * D_)   // 4194304
#define WN ((size_t)D_ * D_)     // 1048576 = 1<<20

struct SwapT { static constexpr bool value = true; };
struct NoSwapT { static constexpr bool value = false; };

// ---------------------------------------------------------------------------
// prep v2: blocks [0,4096) = fp32->bf16 bulk convert, 16 elems/thread
// (4x float4 read = 64 B/lane, 2x uint4 write = 32 B/lane - half the issue
// count of v1's 8-elem version; G13 applied);
// blocks [4096,5120) = mask tile flags (flags[qt][kt] = any-zero in 64x64).
// All segment sizes (QN, WN) are multiples of 16 -> same select logic.
// ---------------------------------------------------------------------------
__global__ __launch_bounds__(256) void prep_kernel(
    const float* __restrict__ q, const float* __restrict__ k, const float* __restrict__ v,
    const float* __restrict__ Wq, const float* __restrict__ Wk,
    const float* __restrict__ Wv, const float* __restrict__ Wo,
    const int* __restrict__ mask,
    unsigned short* __restrict__ qb, unsigned short* __restrict__ kb,
    unsigned short* __restrict__ vb, unsigned short* __restrict__ wqb,
    unsigned short* __restrict__ wkb, unsigned short* __restrict__ wvb,
    unsigned short* __restrict__ wob, int* __restrict__ flags) {
    __shared__ int anyz;
    if (blockIdx.x < 4096) {
        size_t i = ((size_t)blockIdx.x * 256 + threadIdx.x) * 16;
        const float* s; unsigned short* d; size_t off;
        if (i < QN)          { s = q; d = qb; off = i; }
        else if (i < 2 * QN) { s = k; d = kb; off = i - QN; }
        else if (i < 3 * QN) { s = v; d = vb; off = i - 2 * QN; }
        else {
            size_t j = i - 3 * QN;
            int wi = (int)(j >> 20);
            s = (wi == 0) ? Wq : (wi == 1) ? Wk : (wi == 2) ? Wv : Wo;
            d = (wi == 0) ? wqb : (wi == 1) ? wkb : (wi == 2) ? wvb : wob;
            off = j & (WN - 1);
        }
        float4 a0 = *(const float4*)(s + off);
        float4 a1 = *(const float4*)(s + off + 4);
        float4 a2 = *(const float4*)(s + off + 8);
        float4 a3 = *(const float4*)(s + off + 12);
        uint4 p0, p1;
        p0.x = pkbf(a0.x, a0.y); p0.y = pkbf(a0.z, a0.w);
        p0.z = pkbf(a1.x, a1.y); p0.w = pkbf(a1.z, a1.w);
        p1.x = pkbf(a2.x, a2.y); p1.y = pkbf(a2.z, a2.w);
        p1.z = pkbf(a3.x, a3.y); p1.w = pkbf(a3.z, a3.w);
        *(uint4*)(d + off)     = p0;
        *(uint4*)(d + off + 8) = p1;
    } else {
        if (threadIdx.x == 0) anyz = 0;
        __syncthreads();
        int bid2 = blockIdx.x - 4096;
        const int qt = bid2 >> 5, kt = bid2 & 31;
        int az = 0;
        for (int i = threadIdx.x; i < 64 * 64; i += 256) {
            int r = i >> 6, c = i & 63;
            az |= (mask[(size_t)(qt * 64 + r) * S_ + kt * 64 + c] == 0) ? 1 : 0;
        }
        if (az) atomicOr(&anyz, 1);
        __syncthreads();
        if (threadIdx.x == 0) flags[qt * 32 + kt] = anyz;
    }
}

// ---------------------------------------------------------------------------
// bf16 GEMM (R3-proven, 57.7 us): C[M,N] = A[M,K] @ W[N,K]^T + bias, *scale.
// BMT x 128 tile, BK=32, 256 thr = 4 waves (2x2), global_load_lds(16B),
// depth-3 counted-vmcnt pipeline (raw s_barrier, no drain in main loop).
// Grouped LDS layout (16 rows x 32 k per group, chunk-major).
// modes: 0 = fp32 out, 1 = bf16 out, 2 = bf16 Vt layout (Vt[(b*H+h)*64+d][s])
// Modes 0/1 run with SWAPPED mfma operands (acc holds C^T fragments).
// ---------------------------------------------------------------------------
struct GemmArgs {
    const unsigned short* A[3];
    const unsigned short* W[3];
    const float* bias[3];
    void* C[3];
    int mode[3];
    float scale[3];
};

template<int BMT>
__global__ __launch_bounds__(256, 3) void gemm_async(GemmArgs ga) {
    constexpr int AG = BMT / 16;   // A groups
    constexpr int MI = BMT / 32;   // acc rows per wave
    constexpr int NK = D_ / 32;    // 32 k-steps
    constexpr int LOADS = (BMT == 128) ? 4 : 3;  // gld16 per wave per stage
    const int z = blockIdx.z;
    const unsigned short* __restrict__ A = ga.A[z];
    const unsigned short* __restrict__ W = ga.W[z];
    const float* __restrict__ bias = ga.bias[z];
    void* C = ga.C[z];
    const int mode = ga.mode[z];
    const float scl = ga.scale[z];

    __shared__ unsigned short As[3][AG * 512];
    __shared__ unsigned short Bs[3][8 * 512];

    const int t    = threadIdx.x;
    const int lane = t & 63;
    const int w    = t >> 6;
    const int fr   = lane & 15;
    const int kq   = lane >> 4;
    const int wrow = w >> 1, wcol = w & 1;
    const int m0 = blockIdx.x * BMT, n0 = blockIdx.y * 128;

    const int sc = lane >> 4;   // chunk
    const int sr = lane & 15;   // row in group

    const unsigned short* ga0;
    const unsigned short* ga1 = nullptr;
    int la0Off, la1Off = 0;
    if constexpr (BMT == 128) {
        ga0 = A + (size_t)(m0 + (2 * w) * 16 + sr) * D_ + sc * 8;
        ga1 = ga0 + 16 * D_;
        la0Off = (2 * w) * 512;
        la1Off = (2 * w + 1) * 512;
    } else {
        ga0 = A + (size_t)(m0 + w * 16 + sr) * D_ + sc * 8;
        la0Off = w * 512;
    }
    const unsigned short* gw0 = W + (size_t)(n0 + (2 * w) * 16 + sr) * D_ + sc * 8;
    const unsigned short* gw1 = gw0 + 16 * D_;
    const int lw0Off = (2 * w) * 512;
    const int lw1Off = (2 * w + 1) * 512;

    int aOff[MI], bOff[4];
#pragma unroll
    for (int mi = 0; mi < MI; ++mi) aOff[mi] = (wrow * MI + mi) * 512 + (kq * 16 + fr) * 8;
#pragma unroll
    for (int ni = 0; ni < 4; ++ni) bOff[ni] = (wcol * 4 + ni) * 512 + (kq * 16 + fr) * 8;

    f32x4 acc[MI][4];
#pragma unroll
    for (int i = 0; i < MI; ++i)
#pragma unroll
        for (int j = 0; j < 4; ++j) acc[i][j] = (f32x4)0.0f;

    auto stage = [&](int buf) {
        gld16(ga0, &As[buf][la0Off]);
        if constexpr (BMT == 128) gld16(ga1, &As[buf][la1Off]);
        gld16(gw0, &Bs[buf][lw0Off]);
        gld16(gw1, &Bs[buf][lw1Off]);
        ga0 += 32; gw0 += 32; gw1 += 32;
        if constexpr (BMT == 128) ga1 += 32;
    };

    auto kloop = [&](auto swc) {
        constexpr bool SW = decltype(swc)::value;
        auto mma_step = [&](int cur) {
            const unsigned short* Ab = As[cur];
            const unsigned short* Bb = Bs[cur];
            bf16x8 af[MI], bfr[4];
#pragma unroll
            for (int mi = 0; mi < MI; ++mi) af[mi] = *(const bf16x8*)&Ab[aOff[mi]];
#pragma unroll
            for (int ni = 0; ni < 4; ++ni) bfr[ni] = *(const bf16x8*)&Bb[bOff[ni]];
#pragma unroll
            for (int mi = 0; mi < MI; ++mi)
#pragma unroll
                for (int ni = 0; ni < 4; ++ni) {
                    if constexpr (SW)
                        acc[mi][ni] = __builtin_amdgcn_mfma_f32_16x16x32_bf16(
                            bfr[ni], af[mi], acc[mi][ni], 0, 0, 0);
                    else
                        acc[mi][ni] = __builtin_amdgcn_mfma_f32_16x16x32_bf16(
                            af[mi], bfr[ni], acc[mi][ni], 0, 0, 0);
                }
        };

        stage(0);               // tile 0 -> buf 0
        stage(1);               // tile 1 -> buf 1
        int cur = 0;
        for (int k0 = 0; k0 < NK - 1; ++k0) {
            __builtin_amdgcn_sched_barrier(0);
            wait_vm<LOADS>();                     // tile k0 resident (own loads)
            __builtin_amdgcn_s_barrier();         // ... for all waves
            __builtin_amdgcn_sched_barrier(0);
            if (k0 + 2 < NK) {
                int pf = (cur >= 1) ? cur - 1 : cur + 2;   // (cur+2)%3
                stage(pf);
            }
            mma_step(cur);
            cur = (cur < 2) ? cur + 1 : 0;
        }
        __builtin_amdgcn_sched_barrier(0);
        wait_vm<0>();                             // final tile: full drain
        __builtin_amdgcn_s_barrier();
        __builtin_amdgcn_sched_barrier(0);
        mma_step(cur);
    };
    if (mode == 2) kloop(NoSwapT{}); else kloop(SwapT{});

    if (mode == 2) {
        // original orientation: row=token=(lane>>4)*4+reg, col=feature=lane&15
        // Vt[((b*H+h)*64+d)*S + s], 4 consecutive s per lane
        unsigned short* Co = (unsigned short*)C;
#pragma unroll
        for (int ni = 0; ni < 4; ++ni) {
            int col = n0 + wcol * 64 + ni * 16 + fr;
            float bv = bias[col];
            int hh = col >> 6, d = col & 63;
#pragma unroll
            for (int mi = 0; mi < MI; ++mi) {
                int tok = m0 + wrow * (BMT / 2) + mi * 16 + kq * 4;
                int bb = tok >> 11, sbase = tok & (S_ - 1);
                uint2 pk;
                pk.x = pkbf((acc[mi][ni][0] + bv) * scl, (acc[mi][ni][1] + bv) * scl);
                pk.y = pkbf((acc[mi][ni][2] + bv) * scl, (acc[mi][ni][3] + bv) * scl);
                *(uint2*)(Co + ((size_t)((bb * H_ + hh) * 64 + d)) * S_ + sbase) = pk;
            }
        }
    } else if (mode == 0) {
        // swapped: row=token=lane&15, 4 consecutive features per lane
        float* Co = (float*)C;
#pragma unroll
        for (int ni = 0; ni < 4; ++ni) {
            int nb = n0 + wcol * 64 + ni * 16 + kq * 4;
            float4 b4 = *(const float4*)&bias[nb];
#pragma unroll
            for (int mi = 0; mi < MI; ++mi) {
                int m = m0 + wrow * (BMT / 2) + mi * 16 + fr;
                float4 o4;
                o4.x = (acc[mi][ni][0] + b4.x) * scl;
                o4.y = (acc[mi][ni][1] + b4.y) * scl;
                o4.z = (acc[mi][ni][2] + b4.z) * scl;
                o4.w = (acc[mi][ni][3] + b4.w) * scl;
                *(float4*)(Co + (size_t)m * D_ + nb) = o4;
            }
        }
    } else {
        unsigned short* Co = (unsigned short*)C;
#pragma unroll
        for (int ni = 0; ni < 4; ++ni) {
            int nb = n0 + wcol * 64 + ni * 16 + kq * 4;
            float4 b4 = *(const float4*)&bias[nb];
#pragma unroll
            for (int mi = 0; mi < MI; ++mi) {
                int m = m0 + wrow * (BMT / 2) + mi * 16 + fr;
                uint2 pk;
                pk.x = pkbf((acc[mi][ni][0] + b4.x) * scl, (acc[mi][ni][1] + b4.y) * scl);
                pk.y = pkbf((acc[mi][ni][2] + b4.z) * scl, (acc[mi][ni][3] + b4.w) * scl);
                *(uint2*)(Co + (size_t)m * D_ + nb) = pk;
            }
        }
    }
}

// ---------------------------------------------------------------------------
// MFMA flash attention v6 (R3-proven, 58.3 us): 8 waves, 128 q-rows/block;
// depth-3 K/V pipeline with counted vmcnt + raw s_barrier.
// Per tile each wave stages 1 KB of K and 1 KB of V (2 gld16); wait
// vmcnt(2) keeps the next tile's loads in flight across the barrier.
// Fixed-shift softmax (Q pre-scaled by (1/8)*log2(e)); raw v_exp_f32;
// Ps XOR-swizzled; XCD-chunked 1D block swizzle.
// LDS = 3*8K(K) + 3*8K(V) + 16K(Ps) = 64 KB -> 2 blocks/CU (16 waves/CU --
// both deviations from this geometry (v7: 1 block, v8: 4 waves) regressed).
// ---------------------------------------------------------------------------
__global__ __launch_bounds__(512, 4) void flash4(
    const unsigned short* __restrict__ Qb, const unsigned short* __restrict__ Kb,
    const unsigned short* __restrict__ Vtg, const int* __restrict__ mask,
    const int* __restrict__ flags, unsigned short* __restrict__ Xb) {
    __shared__ unsigned short Ks[3][4096];
    __shared__ unsigned short Vs[3][4096];
    __shared__ unsigned short Ps[8192];

    const int t    = threadIdx.x;
    const int lane = t & 63;
    const int w    = t >> 6;     // wave 0..7
    const int fr   = lane & 15;
    const int kq   = lane >> 4;
    // XCD-chunked swizzle of linear block id (nwg=512, 8 XCDs, 64/XCD)
    const int bid = blockIdx.x;
    const int swb = ((bid & 7) << 6) | (bid >> 3);
    const int qt = swb & 15, hd = (swb >> 4) & 15, b = swb >> 8;
    const int q0 = qt * 128;
    const int swz = fr & 7;

    // Q B-frags straight from global (one-time row gather)
    const unsigned short* qrow_p = Qb + (size_t)(b * S_ + q0 + w * 16 + fr) * D_ + hd * 64;
    bf16x8 qf[2];
    qf[0] = *(const bf16x8*)(qrow_p + kq * 8);
    qf[1] = *(const bf16x8*)(qrow_p + 32 + kq * 8);

    // per-wave mask-tile flags (q-tile = qt*2 + (w>>2)) -> bitmask over kt
    int fl = (lane < 32) ? flags[(qt * 2 + (w >> 2)) * 32 + lane] : 0;
    unsigned int fmask = (unsigned int)__ballot(fl != 0);

    // staging: wave w fills LDS shorts [w*512, w*512+512)
    const unsigned short* kptr =
        Kb + (size_t)(b * S_ + (w >> 1) * 16 + fr) * D_ + hd * 64 + (w & 1) * 32 + kq * 8;
    const unsigned short* vptr =
        Vtg + ((size_t)((b * H_ + hd) * 64 + (w >> 1) * 16 + fr)) * S_ + (w & 1) * 32 + kq * 8;

    // prologue: tiles 0,1 into bufs 0,1 (FIFO: K then V per tile)
    gld16(kptr, (char*)&Ks[0][0] + w * 1024);
    gld16(vptr, (char*)&Vs[0][0] + w * 1024);
    gld16(kptr + (size_t)64 * D_, (char*)&Ks[1][0] + w * 1024);
    gld16(vptr + 64,              (char*)&Vs[1][0] + w * 1024);
    const unsigned short* kpf = kptr + (size_t)128 * D_;
    const unsigned short* vpf = vptr + 128;

    // hoisted Ps write/read addresses (loop-invariant)
    unsigned short* pswr[4];
#pragma unroll
    for (int mi = 0; mi < 4; ++mi) {
        int chunk = mi * 2 + (kq >> 1);
        pswr[mi] = &Ps[(w * 16 + fr) * 64 + ((chunk ^ swz) << 3) + ((kq & 1) << 2)];
    }
    const unsigned short* psrd[2];
#pragma unroll
    for (int kk = 0; kk < 2; ++kk) {
        int c = kk * 4 + kq;
        psrd[kk] = &Ps[(w * 16 + fr) * 64 + ((c ^ swz) << 3)];
    }

    const f32x4 zf = (f32x4)0.0f;   // persistent zero C-operand
    f32x4 o[4];
#pragma unroll
    for (int i = 0; i < 4; ++i) o[i] = zf;
    float2v l2 = {0.0f, 0.0f};

    auto attn_step = [&](int cur, int kt) {
        // S^T = K . Q^T : D[key][qrow]; scores already in exp2 domain.
        f32x4 st[4];
#pragma unroll
        for (int mi = 0; mi < 4; ++mi) {
            bf16x8 a = *(const bf16x8*)&Ks[cur][mi * 1024 + (kq * 16 + fr) * 8];
            st[mi] = __builtin_amdgcn_mfma_f32_16x16x32_bf16(a, qf[0], zf, 0, 0, 0);
        }
#pragma unroll
        for (int mi = 0; mi < 4; ++mi) {
            bf16x8 a = *(const bf16x8*)&Ks[cur][mi * 1024 + ((4 + kq) * 16 + fr) * 8];
            st[mi] = __builtin_amdgcn_mfma_f32_16x16x32_bf16(a, qf[1], st[mi], 0, 0, 0);
        }

        if ((fmask >> kt) & 1u) {
            // lane's qrow = q0 + w*16 + fr; keys kt*64 + mi*16 + kq*4 + r
#pragma unroll
            for (int mi = 0; mi < 4; ++mi) {
                int4 mv = *(const int4*)&mask[(size_t)(q0 + w * 16 + fr) * S_ + kt * 64 + mi * 16 + kq * 4];
                if (mv.x == 0) st[mi][0] = -3e8f;
                if (mv.y == 0) st[mi][1] = -3e8f;
                if (mv.z == 0) st[mi][2] = -3e8f;
                if (mv.w == 0) st[mi][3] = -3e8f;
            }
        }

        // P = exp2(s), accumulate l as packed f32x2, pack bf16 into swizzled Ps
#pragma unroll
        for (int mi = 0; mi < 4; ++mi) {
            float e0 = __builtin_amdgcn_exp2f(st[mi][0]);
            float e1 = __builtin_amdgcn_exp2f(st[mi][1]);
            float e2 = __builtin_amdgcn_exp2f(st[mi][2]);
            float e3 = __builtin_amdgcn_exp2f(st[mi][3]);
            l2 += (float2v){e0, e1} + (float2v){e2, e3};
            uint2 pk;
            pk.x = pkbf(e0, e1);
            pk.y = pkbf(e2, e3);
            *(uint2*)pswr[mi] = pk;
        }

        // O^T += Vt . P^T  (A-frags from Vs[d][key], B-frags from swizzled Ps)
#pragma unroll
        for (int kk = 0; kk < 2; ++kk) {
            bf16x8 pb = *(const bf16x8*)psrd[kk];
#pragma unroll
            for (int mi = 0; mi < 4; ++mi) {
                bf16x8 a = *(const bf16x8*)&Vs[cur][mi * 1024 + ((kk * 4 + kq) * 16 + fr) * 8];
                o[mi] = __builtin_amdgcn_mfma_f32_16x16x32_bf16(a, pb, o[mi], 0, 0, 0);
            }
        }
    };

    int cur = 0;
    for (int kt = 0; kt < 31; ++kt) {
        __builtin_amdgcn_sched_barrier(0);
        wait_vm<2>();                       // tile kt resident (own loads)
        __builtin_amdgcn_s_barrier();       // ... for all waves
        __builtin_amdgcn_sched_barrier(0);
        if (kt < 30) {
            int pf = (cur >= 1) ? cur - 1 : cur + 2;   // (cur+2)%3
            gld16(kpf, (char*)&Ks[pf][0] + w * 1024);
            gld16(vpf, (char*)&Vs[pf][0] + w * 1024);
            kpf += (size_t)64 * D_;
            vpf += 64;
        }
        attn_step(cur, kt);
        cur = (cur < 2) ? cur + 1 : 0;
    }
    __builtin_amdgcn_sched_barrier(0);
    wait_vm<0>();                           // last tile: full drain
    __builtin_amdgcn_s_barrier();
    __builtin_amdgcn_sched_barrier(0);
    attn_step(cur, 31);

    // single final l reduction across the 4 kq lane-groups
    float l_i = l2.x + l2.y;
    l_i += __shfl_xor(l_i, 16, 64);
    l_i += __shfl_xor(l_i, 32, 64);
    float rl = 1.0f / l_i;

    // write X (bf16, aliases Q-projection buffer; block rows exclusive)
#pragma unroll
    for (int mi = 0; mi < 4; ++mi) {
        uint2 pk;
        pk.x = pkbf(o[mi][0] * rl, o[mi][1] * rl);
        pk.y = pkbf(o[mi][2] * rl, o[mi][3] * rl);
        *(uint2*)(Xb + (size_t)(b * S_ + q0 + w * 16 + fr) * D_ + hd * 64 + mi * 16 + kq * 4) = pk;
    }
}

// ---------------------------------------------------------------------------
extern "C" void kernel_launch(void* const* d_in, const int* in_sizes, int n_in,
                              void* d_out, int out_size, void* d_ws, size_t ws_size,
                              hipStream_t stream) {
    const float* q    = (const float*)d_in[0];
    const float* k    = (const float*)d_in[1];
    const float* v    = (const float*)d_in[2];
    const int*   mask = (const int*)d_in[3];
    const float* Wq   = (const float*)d_in[4];
    const float* bq   = (const float*)d_in[5];
    const float* Wk   = (const float*)d_in[6];
    const float* bk   = (const float*)d_in[7];
    const float* Wv   = (const float*)d_in[8];
    const float* bv   = (const float*)d_in[9];
    const float* Wo   = (const float*)d_in[10];
    const float* bo   = (const float*)d_in[11];
    float* out = (float*)d_out;

    // workspace (shorts): qb kb vb | Qf Kf Vt | wqb wkb wvb wob | flags  (~59 MB)
    unsigned short* qb  = (unsigned short*)d_ws;
    unsigned short* kb  = qb + QN;
    unsigned short* vb  = kb + QN;
    unsigned short* Qf  = vb + QN;
    unsigned short* Kf  = Qf + QN;
    unsigned short* Vt  = Kf + QN;
    unsigned short* wqb = Vt + QN;
    unsigned short* wkb = wqb + WN;
    unsigned short* wvb = wkb + WN;
    unsigned short* wob = wvb + WN;
    int* flags = (int*)(wob + WN);

    const float SC = 0.18033688011112042f;  // (1/8) * log2(e)

    prep_kernel<<<5120, 256, 0, stream>>>(q, k, v, Wq, Wk, Wv, Wo, mask,
                                          qb, kb, vb, wqb, wkb, wvb, wob, flags);

    GemmArgs g1;
    g1.A[0] = qb;  g1.W[0] = wqb; g1.bias[0] = bq; g1.C[0] = Qf; g1.mode[0] = 1; g1.scale[0] = SC;
    g1.A[1] = kb;  g1.W[1] = wkb; g1.bias[1] = bk; g1.C[1] = Kf; g1.mode[1] = 1; g1.scale[1] = 1.0f;
    g1.A[2] = vb;  g1.W[2] = wvb; g1.bias[2] = bv; g1.C[2] = Vt; g1.mode[2] = 2; g1.scale[2] = 1.0f;
    gemm_async<128><<<dim3(NTOK / 128, D_ / 128, 3), 256, 0, stream>>>(g1);

    flash4<<<dim3((S_ / 128) * H_ * B_, 1, 1), 512, 0, stream>>>(Qf, Kf, Vt, mask, flags, Qf);

    GemmArgs g2;
    g2.A[0] = Qf; g2.W[0] = wob; g2.bias[0] = bo; g2.C[0] = out; g2.mode[0] = 0; g2.scale[0] = 1.0f;
    g2.A[1] = g2.A[2] = nullptr; g2.W[1] = g2.W[2] = nullptr;
    g2.bias[1] = g2.bias[2] = nullptr; g2.C[1] = g2.C[2] = nullptr;
    g2.mode[1] = g2.mode[2] = 0; g2.scale[1] = g2.scale[2] = 1.0f;
    gemm_async<64><<<dim3(NTOK / 64, D_ / 128, 1), 256, 0, stream>>>(g2);
}